// Round 2
// baseline (76.306 us; speedup 1.0000x reference)
//
#include <hip/hip_runtime.h>
#include <hip/hip_bf16.h>
#include <math.h>

// FGN layer, R10 — single-kernel consolidation:
//   res = (X @ W^T + bias) * g,  g = exp(-(sum_k x^2 s^2 - 2 x c s^2 + c^2 s^2))
// R9's two-pass experiment proved the kernel is NOT byte-bound (2.4x byte cut
// -> ~1.6 us): unique inputs (4 MB) are L2/L3-served after first touch. So
// R10 removes the prep pass + workspace round-trip + one launch gap entirely:
// ONE kernel, 128m x 32n tile, grid 256 (1 block/CU), 8 waves (4m x 2n, each
// wave two 16x16 m-frags), inline fp32->bf16 conversion, single-buffered LDS
// (49.7 KB), next-tile loads issued before COMPUTE to overlap MFMA.
// XCD locality: m-tile = b&7 so default round-robin (b%8) keeps one X-panel
// + its 32 n-tiles' W/C/IC panels (~3.1 MB) inside one XCD's 4 MB L2.
// cz = sum c^2 s^2 precomputed per n-row via fp32 partials + 8-lane shfl.

typedef __attribute__((ext_vector_type(8))) short short8;
typedef __attribute__((ext_vector_type(4))) float floatx4;

#define MFMA __builtin_amdgcn_mfma_f32_16x16x32_bf16
#define KSTR 72   // ushort row stride (144 B: 16B-aligned, <=2-way bank alias)

__device__ __forceinline__ unsigned pkbf(float a, float b) {
    union { __hip_bfloat162 h; unsigned u; } v;
    v.h = __float22bfloat162_rn(make_float2(a, b));
    return v.u;
}

__global__ __launch_bounds__(512)
void fgn_one(const float* __restrict__ X, const float* __restrict__ W,
             const float* __restrict__ Bias, const float* __restrict__ C,
             const float* __restrict__ IC, float* __restrict__ Out)
{
    __shared__ __align__(16) unsigned short As [128 * KSTR];  // bf16(x)
    __shared__ __align__(16) unsigned short As2[128 * KSTR];  // bf16(x^2)
    __shared__ __align__(16) unsigned short Bw [32 * KSTR];   // bf16(w)
    __shared__ __align__(16) unsigned short Bg1[32 * KSTR];   // bf16(-2 c s^2)
    __shared__ __align__(16) unsigned short Bg2[32 * KSTR];   // bf16(s^2)
    __shared__ float sCz[32];

    const int b  = blockIdx.x;            // 0..255
    const int m0 = (b & 7) * 128;         // XCD-locality: b%8 owns one m-panel
    const int n0 = (b >> 3) * 32;

    const int t    = threadIdx.x;
    const int w    = t >> 6;
    const int lane = t & 63;
    const int r    = lane & 15;
    const int q    = lane >> 4;
    const int mt   = w & 3;               // wave m-quadrant (32 rows each)
    const int nt   = w >> 2;              // wave n-quadrant (16 cols each)

    // staging coordinates
    const int arow = t >> 3;              // A rows arow and arow+64
    const int ach  = (t & 7) << 3;        // 8-float k-chunk
    const bool isW = (t < 256);           // waves 0-3: W ; waves 4-7: C+IC
    const int brow = (t & 255) >> 3;      // 0..31

    float4 xa0, xa1, xb0, xb1;            // X rows arow / arow+64
    float4 w0, w1, c0, c1, i0, i1;        // B-side operands
    float czp = 0.f;

    floatx4 zero = {0.f, 0.f, 0.f, 0.f};
    floatx4 accL0 = zero, accL1 = zero, accG0 = zero, accG1 = zero;

    auto LOADS = [&](int k0) {
        const float4* p;
        p = (const float4*)&X[(size_t)(m0 + arow) * 256 + k0 + ach];
        xa0 = p[0]; xa1 = p[1];
        p = (const float4*)&X[(size_t)(m0 + arow + 64) * 256 + k0 + ach];
        xb0 = p[0]; xb1 = p[1];
        if (isW) {
            p = (const float4*)&W[(size_t)(n0 + brow) * 256 + k0 + ach];
            w0 = p[0]; w1 = p[1];
        } else {
            p = (const float4*)&C[(size_t)(n0 + brow) * 256 + k0 + ach];
            c0 = p[0]; c1 = p[1];
            p = (const float4*)&IC[(size_t)(n0 + brow) * 256 + k0 + ach];
            i0 = p[0]; i1 = p[1];
        }
    };

    auto STORE_LDS = [&](bool last) {
        {   // A rows: bf16(x), bf16(x^2)
            float f0[8] = {xa0.x,xa0.y,xa0.z,xa0.w, xa1.x,xa1.y,xa1.z,xa1.w};
            float f1[8] = {xb0.x,xb0.y,xb0.z,xb0.w, xb1.x,xb1.y,xb1.z,xb1.w};
            const int a0 = arow * KSTR + ach;
            const int a1 = (arow + 64) * KSTR + ach;
            *(uint4*)&As [a0] = make_uint4(pkbf(f0[0],f0[1]), pkbf(f0[2],f0[3]),
                                           pkbf(f0[4],f0[5]), pkbf(f0[6],f0[7]));
            *(uint4*)&As2[a0] = make_uint4(pkbf(f0[0]*f0[0],f0[1]*f0[1]),
                                           pkbf(f0[2]*f0[2],f0[3]*f0[3]),
                                           pkbf(f0[4]*f0[4],f0[5]*f0[5]),
                                           pkbf(f0[6]*f0[6],f0[7]*f0[7]));
            *(uint4*)&As [a1] = make_uint4(pkbf(f1[0],f1[1]), pkbf(f1[2],f1[3]),
                                           pkbf(f1[4],f1[5]), pkbf(f1[6],f1[7]));
            *(uint4*)&As2[a1] = make_uint4(pkbf(f1[0]*f1[0],f1[1]*f1[1]),
                                           pkbf(f1[2]*f1[2],f1[3]*f1[3]),
                                           pkbf(f1[4]*f1[4],f1[5]*f1[5]),
                                           pkbf(f1[6]*f1[6],f1[7]*f1[7]));
        }
        const int bb = brow * KSTR + ach;
        if (isW) {
            float f[8] = {w0.x,w0.y,w0.z,w0.w, w1.x,w1.y,w1.z,w1.w};
            *(uint4*)&Bw[bb] = make_uint4(pkbf(f[0],f[1]), pkbf(f[2],f[3]),
                                          pkbf(f[4],f[5]), pkbf(f[6],f[7]));
        } else {
            float cf[8] = {c0.x,c0.y,c0.z,c0.w, c1.x,c1.y,c1.z,c1.w};
            float ff[8] = {i0.x,i0.y,i0.z,i0.w, i1.x,i1.y,i1.z,i1.w};
            float g1[8], g2[8];
            #pragma unroll
            for (int e = 0; e < 8; ++e) {
                float s  = fminf(ff[e], 1e8f);
                float qq = s * s;
                g2[e] = qq;
                g1[e] = -2.f * cf[e] * qq;
                czp  = fmaf(cf[e] * cf[e], qq, czp);
            }
            *(uint4*)&Bg1[bb] = make_uint4(pkbf(g1[0],g1[1]), pkbf(g1[2],g1[3]),
                                           pkbf(g1[4],g1[5]), pkbf(g1[6],g1[7]));
            *(uint4*)&Bg2[bb] = make_uint4(pkbf(g2[0],g2[1]), pkbf(g2[2],g2[3]),
                                           pkbf(g2[4],g2[5]), pkbf(g2[6],g2[7]));
            if (last) {   // finalize cz before the barrier
                czp += __shfl_down(czp, 4);
                czp += __shfl_down(czp, 2);
                czp += __shfl_down(czp, 1);
                if ((t & 7) == 0) sCz[brow] = czp;
            }
        }
    };

    const int ar0 = (mt * 32 + r) * KSTR;
    const int ar1 = ar0 + 16 * KSTR;
    const int br  = (nt * 16 + r) * KSTR;
    auto COMPUTE = [&]() {
        #pragma unroll
        for (int kk = 0; kk < 2; ++kk) {
            const int ko = kk * 32 + q * 8;
            short8 a00 = *(const short8*)&As [ar0 + ko];
            short8 a01 = *(const short8*)&As [ar1 + ko];
            short8 a20 = *(const short8*)&As2[ar0 + ko];
            short8 a21 = *(const short8*)&As2[ar1 + ko];
            short8 bwf = *(const short8*)&Bw [br + ko];
            short8 b1f = *(const short8*)&Bg1[br + ko];
            short8 b2f = *(const short8*)&Bg2[br + ko];
            accL0 = MFMA(a00, bwf, accL0, 0, 0, 0);
            accL1 = MFMA(a01, bwf, accL1, 0, 0, 0);
            accG0 = MFMA(a00, b1f, accG0, 0, 0, 0);
            accG1 = MFMA(a01, b1f, accG1, 0, 0, 0);
            accG0 = MFMA(a20, b2f, accG0, 0, 0, 0);
            accG1 = MFMA(a21, b2f, accG1, 0, 0, 0);
        }
    };

    LOADS(0);
    #pragma unroll
    for (int k0 = 0; k0 < 256; k0 += 64) {
        __syncthreads();                  // prev COMPUTE done before overwrite
        STORE_LDS(k0 == 192);
        __syncthreads();
        if (k0 < 192) LOADS(k0 + 64);     // issue next tile; MFMA covers latency
        COMPUTE();
    }

    // epilogue straight from registers
    const int   n    = n0 + nt * 16 + r;
    const float bias = Bias[n];
    const float cz   = sCz[nt * 16 + r];
    float* OutG = Out + (size_t)1024 * 1024;
    #pragma unroll
    for (int reg = 0; reg < 4; ++reg) {
        const int ma = m0 + mt * 32 + q * 4 + reg;
        const float ga   = expf(-(accG0[reg] + cz));
        Out [(size_t)ma * 1024 + n] = (accL0[reg] + bias) * ga;
        OutG[(size_t)ma * 1024 + n] = ga;
        const int mb = ma + 16;
        const float gb   = expf(-(accG1[reg] + cz));
        Out [(size_t)mb * 1024 + n] = (accL1[reg] + bias) * gb;
        OutG[(size_t)mb * 1024 + n] = gb;
    }
}

extern "C" void kernel_launch(void* const* d_in, const int* in_sizes, int n_in,
                              void* d_out, int out_size, void* d_ws, size_t ws_size,
                              hipStream_t stream) {
    const float* X    = (const float*)d_in[0];
    const float* W    = (const float*)d_in[1];
    const float* Bias = (const float*)d_in[2];
    const float* C    = (const float*)d_in[3];
    const float* IC   = (const float*)d_in[4];
    float* Out = (float*)d_out;

    fgn_one<<<256, 512, 0, stream>>>(X, W, Bias, C, IC, Out);
}

// Round 3
// 71.577 us; speedup vs baseline: 1.0661x; 1.0661x over previous
//
#include <hip/hip_runtime.h>
#include <hip/hip_bf16.h>
#include <math.h>

// FGN layer, single fused kernel, R11 == R8 (proven best: 70.86/71.0 us).
//   res = (X @ W^T + bias) * g
//   g   = exp(-(sum_k x^2*s^2 - 2*x*c*s^2 + c^2*s^2)),  s = min(ic, 1e8)
// Block = 32m x 32n, 256 thr; each of 4 waves computes one 16x16 quadrant
// (3 MFMA streams: x*w, x*(-2cs^2), x^2*s^2). Grid 1024 = 4 blocks/CU
// = 4 waves/SIMD to hide cold-HBM staging latency.
// Session triangulation (R9/R10): kernel is latency/occupancy-bound, NOT
// byte-bound — 2.4x byte cuts were neutral (R9) or regressed at 1 block/CU
// (R10, +5.7 us). This structure is the measured optimum; remaining dur_us
// is ~41 us harness poison-fill (80-84% HBM peak) + harness resets.
// LDS ~23 KB/block; cz = sum c^2 s^2 via fp32 partials + 8-lane shfl.

typedef __attribute__((ext_vector_type(8))) short short8;
typedef __attribute__((ext_vector_type(4))) float floatx4;

#define MFMA __builtin_amdgcn_mfma_f32_16x16x32_bf16
#define INDIM 256
#define OUTD  1024
#define BD    1024
#define TM 32
#define TN 32
#define TK 64
#define KSTR 72   // ushort stride (144 B: b128-aligned, <=2-way bank alias = free)

__device__ __forceinline__ unsigned pkbf(float a, float b) {
    union { __hip_bfloat162 h; unsigned u; } v;
    v.h = __float22bfloat162_rn(make_float2(a, b));
    return v.u;
}

__global__ __launch_bounds__(256)
void fgn_fused(const float* __restrict__ X, const float* __restrict__ W,
               const float* __restrict__ Bias, const float* __restrict__ C,
               const float* __restrict__ IC, float* __restrict__ Out)
{
    __shared__ __align__(16) unsigned short As [TM * KSTR];
    __shared__ __align__(16) unsigned short As2[TM * KSTR];
    __shared__ __align__(16) unsigned short Bw [TN * KSTR];
    __shared__ __align__(16) unsigned short Bg1[TN * KSTR];
    __shared__ __align__(16) unsigned short Bg2[TN * KSTR];
    __shared__ float sCz[TN];

    // XCD-aware swizzle: xcd = b%8 owns n-cols {xcd, xcd+8, xcd+16, xcd+24}
    const int b    = blockIdx.x;              // 0..1023
    const int xcd  = b & 7;
    const int n0   = (xcd + 8 * ((b >> 3) & 3)) * TN;
    const int m0   = (b >> 5) * TM;

    const int t    = threadIdx.x;
    const int w    = t >> 6;                  // wave id
    const int lane = t & 63;
    const int r    = lane & 15;
    const int q    = lane >> 4;
    const int mt   = w & 1;                   // wave's m-quadrant
    const int nt   = w >> 1;                  // wave's n-quadrant

    // staging coordinates: 32 rows, 8 k's (2 float4) per thread
    const int srow = t >> 3;                  // 0..31
    const int sk   = (t & 7) << 3;            // 0..56

    floatx4 zero = {0.f, 0.f, 0.f, 0.f};
    floatx4 accL = zero;
    floatx4 accG = zero;
    float czp = 0.f;

    for (int k0 = 0; k0 < INDIM; k0 += TK) {
        // ---- global loads (issued before the barrier: overlap prior compute)
        const float4* xp = (const float4*)&X[(size_t)(m0 + srow) * INDIM + k0 + sk];
        float4 x0 = xp[0], x1 = xp[1];
        const size_t bo = (size_t)(n0 + srow) * INDIM + k0 + sk;
        const float4* wp = (const float4*)&W[bo];
        const float4* cp = (const float4*)&C[bo];
        const float4* ip = (const float4*)&IC[bo];
        float4 w0 = wp[0], w1 = wp[1];
        float4 c0 = cp[0], c1 = cp[1];
        float4 i0 = ip[0], i1 = ip[1];

        __syncthreads();   // previous tile's compute done before LDS overwrite

        // ---- stage A: bf16(x), bf16(x^2)
        {
            float xf[8] = {x0.x,x0.y,x0.z,x0.w, x1.x,x1.y,x1.z,x1.w};
            uint4* pa  = (uint4*)&As [srow * KSTR + sk];
            uint4* pa2 = (uint4*)&As2[srow * KSTR + sk];
            pa[0]  = make_uint4(pkbf(xf[0],xf[1]), pkbf(xf[2],xf[3]),
                                pkbf(xf[4],xf[5]), pkbf(xf[6],xf[7]));
            pa2[0] = make_uint4(pkbf(xf[0]*xf[0],xf[1]*xf[1]), pkbf(xf[2]*xf[2],xf[3]*xf[3]),
                                pkbf(xf[4]*xf[4],xf[5]*xf[5]), pkbf(xf[6]*xf[6],xf[7]*xf[7]));
        }
        // ---- stage B: bf16(w), bf16(-2*c*s^2), bf16(s^2); fp32 cz partial
        {
            float wf[8] = {w0.x,w0.y,w0.z,w0.w, w1.x,w1.y,w1.z,w1.w};
            float cf[8] = {c0.x,c0.y,c0.z,c0.w, c1.x,c1.y,c1.z,c1.w};
            float ff[8] = {i0.x,i0.y,i0.z,i0.w, i1.x,i1.y,i1.z,i1.w};
            float g1[8], g2[8];
            #pragma unroll
            for (int e = 0; e < 8; ++e) {
                float s  = fminf(ff[e], 1e8f);
                float qq = s * s;
                g2[e] = qq;
                g1[e] = -2.f * cf[e] * qq;
                czp  = fmaf(cf[e] * cf[e], qq, czp);
            }
            const int bb = srow * KSTR + sk;
            *(uint4*)&Bw [bb] = make_uint4(pkbf(wf[0],wf[1]), pkbf(wf[2],wf[3]),
                                           pkbf(wf[4],wf[5]), pkbf(wf[6],wf[7]));
            *(uint4*)&Bg1[bb] = make_uint4(pkbf(g1[0],g1[1]), pkbf(g1[2],g1[3]),
                                           pkbf(g1[4],g1[5]), pkbf(g1[6],g1[7]));
            *(uint4*)&Bg2[bb] = make_uint4(pkbf(g2[0],g2[1]), pkbf(g2[2],g2[3]),
                                           pkbf(g2[4],g2[5]), pkbf(g2[6],g2[7]));
        }
        if (k0 + TK >= INDIM) {   // last tile: finalize cz before the barrier
            czp += __shfl_down(czp, 4);
            czp += __shfl_down(czp, 2);
            czp += __shfl_down(czp, 1);
            if ((t & 7) == 0) sCz[srow] = czp;
        }
        __syncthreads();

        // ---- compute: 2 k-steps of 32
        #pragma unroll
        for (int kk = 0; kk < 2; ++kk) {
            const int ko = kk * 32 + q * 8;
            short8 a0  = *(const short8*)&As [(mt * 16 + r) * KSTR + ko];
            short8 a2  = *(const short8*)&As2[(mt * 16 + r) * KSTR + ko];
            const int br = (nt * 16 + r) * KSTR + ko;
            short8 bwf = *(const short8*)&Bw [br];
            short8 b1f = *(const short8*)&Bg1[br];
            short8 b2f = *(const short8*)&Bg2[br];
            accL = MFMA(a0, bwf, accL, 0, 0, 0);
            accG = MFMA(a0, b1f, accG, 0, 0, 0);
            accG = MFMA(a2, b2f, accG, 0, 0, 0);
        }
    }

    // ---- epilogue straight from registers
    float* OutR = Out;
    float* OutG = Out + (size_t)BD * OUTD;
    const int n      = n0 + nt * 16 + r;
    const float bias = Bias[n];
    const float cz   = sCz[nt * 16 + r];
    #pragma unroll
    for (int reg = 0; reg < 4; ++reg) {
        const int m = m0 + mt * 16 + q * 4 + reg;
        const float g   = expf(-(accG[reg] + cz));
        const float res = (accL[reg] + bias) * g;
        OutR[(size_t)m * OUTD + n] = res;
        OutG[(size_t)m * OUTD + n] = g;
    }
}

extern "C" void kernel_launch(void* const* d_in, const int* in_sizes, int n_in,
                              void* d_out, int out_size, void* d_ws, size_t ws_size,
                              hipStream_t stream) {
    const float* X    = (const float*)d_in[0];
    const float* W    = (const float*)d_in[1];
    const float* Bias = (const float*)d_in[2];
    const float* C    = (const float*)d_in[3];
    const float* IC   = (const float*)d_in[4];
    float* Out = (float*)d_out;

    fgn_fused<<<1024, 256, 0, stream>>>(X, W, Bias, C, IC, Out);
}